// Round 6
// baseline (824.641 us; speedup 1.0000x reference)
//
#include <hip/hip_runtime.h>

constexpr int UNITS = 10;
constexpr int TIN = 50;
constexpr int TOUT = 3;
constexpr int G4 = 4 * UNITS;
constexpr int BLK = 256;

// d_ws float layout:
//   [0..39]    W1g   : gate-major (gate*10+j), i/f/o cols scaled by -log2(e)
//   [40..79]   b1g   : same
//   [80..479]  R1g   : gate*100 + u*10 + j  (transposed to chunk-contiguous)
//   [480..879] W2s   : row-major u*40+g, i/f/o cols scaled
//   [880..919] b2s   : scaled
//   [920..1319]R2s   : row-major v*40+g, i/f/o cols scaled
constexpr float NEG_LOG2E = -1.44269504088896341f;

__global__ void prep_weights(const float* __restrict__ W1, const float* __restrict__ R1,
                             const float* __restrict__ b1, const float* __restrict__ W2,
                             const float* __restrict__ R2, const float* __restrict__ b2,
                             float* __restrict__ ws)
{
    const int tid = threadIdx.x;
    // W1g / b1g: cols already gate-blocked (i:0-9 f:10-19 g:20-29 o:30-39)
    if (tid < G4) {
        const int gate = tid / 10;
        const float s = (gate == 2) ? 1.0f : NEG_LOG2E;
        ws[tid]      = W1[tid] * s;
        ws[40 + tid] = b1[tid] * s;
        ws[880 + tid] = b2[tid] * s;
    }
    // R1g[gate*100 + u*10 + j] = R1[u*40 + gate*10 + j] * s(gate)
    for (int i = tid; i < 400; i += BLK) {
        const int gate = i / 100, r = i % 100, u = r / 10, j = r % 10;
        const float s = (gate == 2) ? 1.0f : NEG_LOG2E;
        ws[80 + i] = R1[u * G4 + gate * 10 + j] * s;
        // W2s / R2s: plain scaled copies, row-major
        const int col = i % G4;
        const float s2 = (col >= 20 && col < 30) ? 1.0f : NEG_LOG2E;
        ws[480 + i] = W2[i] * s2;
        ws[920 + i] = R2[i] * s2;
    }
}

__device__ __forceinline__ float sig_pre(float zs) {
    // zs already scaled by -log2(e): sigmoid = 1/(1+2^zs). v_exp_f32 IS 2^x.
    return __builtin_amdgcn_rcpf(1.0f + __builtin_amdgcn_exp2f(zs));
}

__global__ __launch_bounds__(BLK) void lstm_ae_kernel(
    const float* __restrict__ X, const float* __restrict__ ws,
    const float* __restrict__ Wd, const float* __restrict__ bd,
    float* __restrict__ out, int B)
{
    const int b = blockIdx.x * BLK + threadIdx.x;
    if (b >= B) return;

    const float* __restrict__ W1g = ws;
    const float* __restrict__ b1g = ws + 40;
    const float* __restrict__ R1g = ws + 80;
    const float* __restrict__ W2s = ws + 480;
    const float* __restrict__ b2s = ws + 880;
    const float* __restrict__ R2s = ws + 920;

    float h[UNITS], c[UNITS];
    #pragma unroll
    for (int u = 0; u < UNITS; ++u) { h[u] = 0.0f; c[u] = 0.0f; }

    // ---------------- LSTM 1: 50 steps, gate-chunked (peak live ~45 VGPR) ---
    // One step. Chunk order g -> i -> f -> o; only zc[10] + pg[10] temps live.
#define CHUNK_DOT(G, zc)                                                     \
    {                                                                        \
        const float* __restrict__ Wg = W1g + (G) * 10;                       \
        const float* __restrict__ Bg = b1g + (G) * 10;                       \
        const float* __restrict__ Rg = R1g + (G) * 100;                      \
        _Pragma("unroll")                                                    \
        for (int j = 0; j < 10; ++j) zc[j] = fmaf(x, Wg[j], Bg[j]);          \
        _Pragma("unroll")                                                    \
        for (int u = 0; u < UNITS; ++u) {                                    \
            const float hu = h[u];                                           \
            _Pragma("unroll")                                                \
            for (int j = 0; j < 10; ++j)                                     \
                zc[j] = fmaf(hu, Rg[u * 10 + j], zc[j]);                     \
        }                                                                    \
    }

#define STEP(xval)                                                           \
    {                                                                        \
        const float x = (xval);                                              \
        float pg[10], zc[10];                                                \
        CHUNK_DOT(2, zc)            /* g-gate: relu(raw z) */                \
        _Pragma("unroll")                                                    \
        for (int j = 0; j < 10; ++j) pg[j] = fmaxf(zc[j], 0.0f);             \
        CHUNK_DOT(0, zc)            /* i-gate */                             \
        _Pragma("unroll")                                                    \
        for (int j = 0; j < 10; ++j) pg[j] *= sig_pre(zc[j]);                \
        CHUNK_DOT(1, zc)            /* f-gate */                             \
        _Pragma("unroll")                                                    \
        for (int j = 0; j < 10; ++j) c[j] = fmaf(sig_pre(zc[j]), c[j], pg[j]); \
        CHUNK_DOT(3, zc)            /* o-gate (uses h_old) */                \
        _Pragma("unroll")                                                    \
        for (int j = 0; j < 10; ++j) h[j] = sig_pre(zc[j]) * fmaxf(c[j], 0.0f); \
    }

    // x: float2 loads, one pair-iteration of software prefetch (~2000cy ahead)
    const float2* __restrict__ xp = (const float2*)(X + (size_t)b * TIN);
    float2 xv = xp[0];
    #pragma unroll 1
    for (int p = 0; p < TIN / 2 - 1; ++p) {
        const float2 xn = xp[p + 1];
        STEP(xv.x)
        STEP(xv.y)
        xv = xn;
    }
    STEP(xv.x)
    STEP(xv.y)
#undef STEP
#undef CHUNK_DOT

    // ---------------- RepeatVector(3) + LSTM 2 ----------------
    float xz2[G4];
    #pragma unroll
    for (int g = 0; g < G4; ++g) {
        float a = b2s[g];
        #pragma unroll
        for (int u = 0; u < UNITS; ++u) a = fmaf(h[u], W2s[u * G4 + g], a);
        xz2[g] = a;
    }

    float h2[UNITS], c2[UNITS];
    float o0;
    {   // t2 = 0: h_prev = c_prev = 0
        float acc = bd[0];
        #pragma unroll
        for (int u = 0; u < UNITS; ++u) {
            const float ig = sig_pre(xz2[u]);
            const float gg = fmaxf(xz2[2 * UNITS + u], 0.0f);
            const float og = sig_pre(xz2[3 * UNITS + u]);
            const float cn = ig * gg;
            c2[u] = cn;
            const float hn = og * fmaxf(cn, 0.0f);
            h2[u] = hn;
            acc = fmaf(hn, Wd[u], acc);
        }
        o0 = acc;
    }

    float oacc[2];
    #pragma unroll
    for (int t2 = 0; t2 < 2; ++t2) {
        float hold[UNITS];
        #pragma unroll
        for (int u = 0; u < UNITS; ++u) hold[u] = h2[u];
        float acc = bd[0];
        #pragma unroll
        for (int u = 0; u < UNITS; ++u) {
            float zi = xz2[u];
            float zf = xz2[UNITS + u];
            float zg = xz2[2 * UNITS + u];
            float zo = xz2[3 * UNITS + u];
            #pragma unroll
            for (int v = 0; v < UNITS; ++v) {
                const float hv = hold[v];
                zi = fmaf(hv, R2s[v * G4 + u], zi);
                zf = fmaf(hv, R2s[v * G4 + UNITS + u], zf);
                zg = fmaf(hv, R2s[v * G4 + 2 * UNITS + u], zg);
                zo = fmaf(hv, R2s[v * G4 + 3 * UNITS + u], zo);
            }
            const float ig = sig_pre(zi);
            const float fg = sig_pre(zf);
            const float gg = fmaxf(zg, 0.0f);
            const float og = sig_pre(zo);
            const float cn = fmaf(fg, c2[u], ig * gg);
            c2[u] = cn;
            const float hn = og * fmaxf(cn, 0.0f);
            h2[u] = hn;
            acc = fmaf(hn, Wd[u], acc);
        }
        oacc[t2] = acc;
    }

    float* __restrict__ o3 = out + (size_t)b * TOUT;
    o3[0] = o0;
    o3[1] = oacc[0];
    o3[2] = oacc[1];
}

extern "C" void kernel_launch(void* const* d_in, const int* in_sizes, int n_in,
                              void* d_out, int out_size, void* d_ws, size_t ws_size,
                              hipStream_t stream) {
    const float* X  = (const float*)d_in[0];
    const float* W1 = (const float*)d_in[1];
    const float* R1 = (const float*)d_in[2];
    const float* b1 = (const float*)d_in[3];
    const float* W2 = (const float*)d_in[4];
    const float* R2 = (const float*)d_in[5];
    const float* b2 = (const float*)d_in[6];
    const float* Wd = (const float*)d_in[7];
    const float* bd = (const float*)d_in[8];
    float* out = (float*)d_out;
    float* ws  = (float*)d_ws;

    const int B = in_sizes[0] / TIN;   // 524288
    prep_weights<<<1, BLK, 0, stream>>>(W1, R1, b1, W2, R2, b2, ws);
    const int grid = (B + BLK - 1) / BLK;
    lstm_ae_kernel<<<grid, BLK, 0, stream>>>(X, ws, Wd, bd, out, B);
}